// Round 18
// baseline (179.723 us; speedup 1.0000x reference)
//
#include <hip/hip_runtime.h>

#define TT 128
#define DD 256
#define NH 8
#define HD 32
#define SCALEF 0.17677669529663687f
#define NEGV -1e9f

typedef short bf16x8 __attribute__((ext_vector_type(8)));
typedef float f32x4 __attribute__((ext_vector_type(4)));

__device__ inline unsigned short f2bf(float f) {
    unsigned u = __float_as_uint(f);
    unsigned r = (u + 0x7FFFu + ((u >> 16) & 1u)) >> 16;
    return (unsigned short)r;
}
__device__ inline unsigned pk2(float a, float b) {
    return (unsigned)f2bf(a) | ((unsigned)f2bf(b) << 16);
}

// ---------------------------------------------------------------------------
// Kernel 0: weights -> bf16 FRAGMENT-LINEAR layouts in ws (unchanged).
// ---------------------------------------------------------------------------
__global__ void cvt_weights_kernel(
    const float* __restrict__ wq, const float* __restrict__ wk,
    const float* __restrict__ vw, const float* __restrict__ ow,
    const unsigned char* __restrict__ kpm8,
    unsigned short* __restrict__ wqf, unsigned short* __restrict__ wkf,
    unsigned short* __restrict__ vwf, unsigned short* __restrict__ owf,
    int* __restrict__ flagp)
{
    if (blockIdx.x == 1280) {
        __shared__ int f;
        if (threadIdx.x == 0) f = 0;
        __syncthreads();
        bool loc = false;
        for (int i = threadIdx.x; i < 4096; i += 256)
            if ((i & 3) && kpm8[i]) loc = true;
        if (loc) f = 1;
        __syncthreads();
        if (threadIdx.x == 0) *flagp = f;
        return;
    }
    int t = blockIdx.x * 256 + threadIdx.x;          // 0..327679
    if (t < 196608) {
        int f = t >> 9, r = t & 511, l = r >> 3, s = r & 7;
        int k = f >> 7, jr = (f >> 3) & 15, c32 = f & 7;
        int j = jr * 16 + (l & 15);
        int ci = c32 * 32 + (l >> 4) * 8 + s;
        int src = j * 768 + ci * 3 + k;
        wqf[t] = f2bf(wq[src]);
        wkf[t] = f2bf(wk[src]);
    } else {
        int o = t - 196608;
        int oo = o & 65535;
        int f = oo >> 9, r = oo & 511, l = r >> 3, s = r & 7;
        int er = f >> 3, c32 = f & 7;
        int e = er * 16 + (l & 15);
        int d = c32 * 32 + (l >> 4) * 8 + s;
        if (o < 65536) vwf[oo] = f2bf(vw[e * 256 + d]);
        else           owf[oo] = f2bf(ow[e * 256 + d]);
    }
}

// ---------------------------------------------------------------------------
// Kernel 1: conv Q/K projections ONLY (V moved into the fused kernel).
// R8-exact plateau structure; grid (512 bn, 2 which) = 1024 blocks = 2
// occupancy rounds instead of 3 -> expected ~2/3 of the 127us.
// ---------------------------------------------------------------------------
#define XP 264   // LDS row pitch in shorts

__global__ __launch_bounds__(512, 4) void proj_kernel(
    const float* __restrict__ query, const float* __restrict__ key,
    const unsigned short* __restrict__ wqf, const unsigned short* __restrict__ wkf,
    const float* __restrict__ bq, const float* __restrict__ bk,
    short* __restrict__ qkb)
{
    __shared__ __align__(16) short Xs[130 * XP];   // 68.6 KB

    const int tid = threadIdx.x;
    const int bn = blockIdx.x, which = blockIdx.y;
    const int lane = tid & 63, wv = tid >> 6;
    const int lr = lane & 15, rg = lane >> 4, k8 = rg * 8;

    const float* __restrict__ X =
        (which == 0 ? query : key) + (size_t)bn * TT * DD;
    const unsigned short* __restrict__ W = which ? wkf : wqf;
    const float* __restrict__ bias = which ? bk : bq;
    const int j0 = (wv & 3) * 64;     // output-channel tile
    const int t0 = (wv >> 2) * 64;    // time tile

    // ---- stage the WHOLE X tile: rows t=-1..128 (halo), 256 ch ----
    for (int i = tid; i < 130 * 64; i += 512) {
        int row = i >> 6, c4 = i & 63, g = row - 1;
        float4 x4 = make_float4(0.f, 0.f, 0.f, 0.f);
        if (g >= 0 && g < TT)
            x4 = *(const float4*)(X + g * DD + c4 * 4);
        uint2 p; p.x = pk2(x4.x, x4.y); p.y = pk2(x4.z, x4.w);
        *(uint2*)&Xs[row * XP + c4 * 4] = p;
    }
    __syncthreads();

    f32x4 acc[4][4];
    #pragma unroll
    for (int mf = 0; mf < 4; ++mf)
        #pragma unroll
        for (int r = 0; r < 4; ++r) {
            float bv = bias[j0 + mf * 16 + rg * 4 + r];
            #pragma unroll
            for (int nf = 0; nf < 4; ++nf) acc[mf][nf][r] = bv;
        }

    // ---- all 24 k-groups, no barriers ----
    #pragma unroll
    for (int k = 0; k < 3; ++k) {
        #pragma unroll
        for (int c32 = 0; c32 < 8; ++c32) {
            bf16x8 aa[4];
            #pragma unroll
            for (int mf = 0; mf < 4; ++mf)
                aa[mf] = *(const bf16x8*)(W +
                    ((((k * 16 + (j0 >> 4) + mf) * 8 + c32) << 9)
                     + lane * 8));
            bf16x8 bb[4];
            #pragma unroll
            for (int nf = 0; nf < 4; ++nf)
                bb[nf] = *(const bf16x8*)&Xs[(t0 + nf * 16 + lr + k) * XP
                                             + c32 * 32 + k8];
            #pragma unroll
            for (int mf = 0; mf < 4; ++mf)
                #pragma unroll
                for (int nf = 0; nf < 4; ++nf)
                    acc[mf][nf] = __builtin_amdgcn_mfma_f32_16x16x32_bf16(
                        aa[mf], bb[nf], acc[mf][nf], 0, 0, 0);
        }
    }
    // frag-linear store: frag (tr*8 + jc), coalesced 512B per (mf,nf)
    short* cell = qkb + (size_t)bn * 65536 + which * 32768;
    #pragma unroll
    for (int mf = 0; mf < 4; ++mf)
        #pragma unroll
        for (int nf = 0; nf < 4; ++nf) {
            int fr = ((t0 >> 4) + nf) * 8 + (j0 >> 5) + (mf >> 1);
            int off = (fr << 9) + (lr + 16 * ((mf & 1) * 2 + (rg >> 1))) * 8
                      + (rg & 1) * 4;
            uint2 p;
            p.x = pk2(acc[mf][nf][0], acc[mf][nf][1]);
            p.y = pk2(acc[mf][nf][2], acc[mf][nf][3]);
            *(uint2*)&cell[off] = p;
        }
}

// ---------------------------------------------------------------------------
// Kernel 2: FUSED V-projection + attention. grid 512 (bn, XCD-swizzled),
// 512 threads / 8 waves; wave = head.
//  Phase A: stage value tile (U region), build maskb.
//  Phase B: V-proj per wave (A = X rows t from LDS, B = vwf frags from L2),
//           V^T written to WAVE-PRIVATE LDS frags (same store formula as the
//           old proj V path; er0 = wv*2, t-chunk = mf>>1).
//  Phase C: per-mtp QK^T -> softmax -> Ps (U region, reused) -> PV (V^T from
//           LDS) -> x transpose via per-wave xlw -> frag-linear bf16 store
//           over this block's own K-cell frags (wave-private; kb consumed in
//           mtp0 before first overwrite).
// LDS 154KB -> 1 block/CU. Out-projection is kernel 3.
// ---------------------------------------------------------------------------
__global__ __launch_bounds__(512, 2) void vproj_attn_fused(
    short* qkb, const float* __restrict__ value,
    const unsigned short* __restrict__ vwf, const float* __restrict__ vbias,
    const unsigned char* __restrict__ kpm8, const int* __restrict__ kpm32,
    const int* __restrict__ amask, const int* __restrict__ flagp)
{
    __shared__ __align__(16) short U[34816];      // 69.6 KB: Xv[128][264] | Ps[8][32][136]
    __shared__ __align__(16) short VsT[32768];    // 65.5 KB: 64 V^T frags
    __shared__ __align__(16) short xlw[8 * 32 * 40];  // 20.5 KB per-wave x transpose
    __shared__ unsigned char maskb[2048];

    const int tid = threadIdx.x;
    const int bid = blockIdx.x;
    const int bn = (bid & 7) * 64 + (bid >> 3);        // XCD swizzle
    const int lane = tid & 63, wv = tid >> 6;          // wv = head
    const int lr = lane & 15, rg = lane >> 4, k8 = rg * 8;
    const bool kpm_u8 = (*flagp != 0);

    // ---- Phase A: stage value tile + maskb ----
    {
        const float* __restrict__ Xv = value + (size_t)bn * TT * DD;
        for (int i = tid; i < 128 * 64; i += 512) {
            int row = i >> 6, c4 = i & 63;
            float4 x4 = *(const float4*)(Xv + row * DD + c4 * 4);
            uint2 p; p.x = pk2(x4.x, x4.y); p.y = pk2(x4.z, x4.w);
            *(uint2*)&U[row * XP + c4 * 4] = p;
        }
        const unsigned char* kp8 = kpm8 + (size_t)bn * TT;
        const int* kp32 = kpm32 + (size_t)bn * TT;
        for (int i = tid; i < 2048; i += 512) {
            int row = i >> 4, c = i & 15;
            unsigned m = 0;
            #pragma unroll
            for (int nf = 0; nf < 8; ++nf) {
                int col = c + nf * 16;
                int kdead = kpm_u8 ? (int)kp8[col] : kp32[col];
                int adead = (amask[row * TT + col] == 0) ? 1 : 0;
                m |= (unsigned)(((kdead != 0) ? 1 : 0) | adead) << nf;
            }
            maskb[i] = (unsigned char)m;
        }
    }
    __syncthreads();   // Xv + maskb ready

    // ---- Phase B: V-proj (wave = head; e slice = wv*32..+32, all 128 t) ----
    {
        f32x4 vacc[8][2];
        #pragma unroll
        for (int nf = 0; nf < 2; ++nf) {
            float bv = vbias[wv * HD + nf * 16 + lr];
            #pragma unroll
            for (int mf = 0; mf < 8; ++mf)
                #pragma unroll
                for (int r = 0; r < 4; ++r) vacc[mf][nf][r] = bv;
        }
        #pragma unroll
        for (int c32 = 0; c32 < 8; ++c32) {
            bf16x8 bb[2];
            #pragma unroll
            for (int nf = 0; nf < 2; ++nf)
                bb[nf] = *(const bf16x8*)(vwf +
                    ((((wv * 2 + nf) * 8 + c32) << 9) + lane * 8));
            bf16x8 aa[8];
            #pragma unroll
            for (int mf = 0; mf < 8; ++mf)
                aa[mf] = *(const bf16x8*)&U[(mf * 16 + lr) * XP
                                            + c32 * 32 + k8];
            #pragma unroll
            for (int mf = 0; mf < 8; ++mf)
                #pragma unroll
                for (int nf = 0; nf < 2; ++nf)
                    vacc[mf][nf] = __builtin_amdgcn_mfma_f32_16x16x32_bf16(
                        aa[mf], bb[nf], vacc[mf][nf], 0, 0, 0);
        }
        // V^T frag store to LDS (wave-private frags): fr = (wv*2+nf)*4 + (mf>>1)
        #pragma unroll
        for (int mf = 0; mf < 8; ++mf)
            #pragma unroll
            for (int nf = 0; nf < 2; ++nf) {
                int fr = (wv * 2 + nf) * 4 + (mf >> 1);
                int off = (fr << 9) + (lr + 16 * ((mf & 1) * 2 + (rg >> 1))) * 8
                          + (rg & 1) * 4;
                uint2 p;
                p.x = pk2(vacc[mf][nf][0], vacc[mf][nf][1]);
                p.y = pk2(vacc[mf][nf][2], vacc[mf][nf][3]);
                *(uint2*)&VsT[off] = p;
            }
    }
    __syncthreads();   // all waves done reading U (Xv) -> U becomes Ps

    const short* qcell = qkb + (size_t)bn * 65536;
    short* kcell = qkb + (size_t)bn * 65536 + 32768;

    // K frags for this head (frags (nf*8 + wv) — this wave's own frag set,
    // consumed fully in mtp0's QK^T before any x overwrite)
    bf16x8 kb[8];
    #pragma unroll
    for (int nf = 0; nf < 8; ++nf)
        kb[nf] = *(const bf16x8*)(kcell + (((nf * 8 + wv) << 9) + lane * 8));

    short* Pw = U + wv * 32 * 136;
    short* xw = xlw + wv * 32 * 40;

    #pragma unroll
    for (int mtp = 0; mtp < 4; ++mtp) {
        // Q frags for this m-tile pair
        bf16x8 qa[2];
        #pragma unroll
        for (int mf = 0; mf < 2; ++mf)
            qa[mf] = *(const bf16x8*)(qcell +
                ((((mtp * 2 + mf) * 8 + wv) << 9) + lane * 8));

        // QK^T
        f32x4 sc[2][8];
        #pragma unroll
        for (int nf = 0; nf < 8; ++nf) {
            f32x4 z = { 0.f, 0.f, 0.f, 0.f };
            sc[0][nf] = __builtin_amdgcn_mfma_f32_16x16x32_bf16(qa[0], kb[nf], z, 0, 0, 0);
            sc[1][nf] = __builtin_amdgcn_mfma_f32_16x16x32_bf16(qa[1], kb[nf], z, 0, 0, 0);
        }

        // mask + softmax (16-lane groups own a row)
        float linv[2][4];
        #pragma unroll
        for (int mf = 0; mf < 2; ++mf)
            #pragma unroll
            for (int r = 0; r < 4; ++r) {
                int row = mtp * 32 + mf * 16 + rg * 4 + r;
                unsigned mb = maskb[row * 16 + lr];
                float v[8];
                float vmax = -3.4e38f;
                #pragma unroll
                for (int nf = 0; nf < 8; ++nf) {
                    float t = sc[mf][nf][r] * SCALEF;
                    if ((mb >> nf) & 1) t = NEGV;
                    v[nf] = t;
                    vmax = fmaxf(vmax, t);
                }
                #pragma unroll
                for (int d = 1; d < 16; d <<= 1)
                    vmax = fmaxf(vmax, __shfl_xor(vmax, d, 64));
                float ls = 0.f;
                #pragma unroll
                for (int nf = 0; nf < 8; ++nf) {
                    float p = __expf(v[nf] - vmax);
                    ls += p;
                    sc[mf][nf][r] = p;
                }
                #pragma unroll
                for (int d = 1; d < 16; d <<= 1)
                    ls += __shfl_xor(ls, d, 64);
                linv[mf][r] = 1.f / ls;
            }

        // P -> wave-private LDS
        #pragma unroll
        for (int mf = 0; mf < 2; ++mf)
            #pragma unroll
            for (int r = 0; r < 4; ++r) {
                int q = mf * 16 + rg * 4 + r;
                #pragma unroll
                for (int nf = 0; nf < 8; ++nf)
                    Pw[q * 136 + nf * 16 + lr] = (short)f2bf(sc[mf][nf][r]);
            }

        // PV: A = P (LDS), B = V^T frags (LDS, wave-private)
        f32x4 xacc[2][2];
        {
            f32x4 z = { 0.f, 0.f, 0.f, 0.f };
            xacc[0][0] = z; xacc[0][1] = z; xacc[1][0] = z; xacc[1][1] = z;
        }
        #pragma unroll
        for (int kk = 0; kk < 4; ++kk) {
            bf16x8 pa0 = *(const bf16x8*)&Pw[lr * 136 + kk * 32 + k8];
            bf16x8 pa1 = *(const bf16x8*)&Pw[(16 + lr) * 136 + kk * 32 + k8];
            bf16x8 vb0 = *(const bf16x8*)&VsT[(((wv * 2 + 0) * 4 + kk) << 9) + lane * 8];
            bf16x8 vb1 = *(const bf16x8*)&VsT[(((wv * 2 + 1) * 4 + kk) << 9) + lane * 8];
            xacc[0][0] = __builtin_amdgcn_mfma_f32_16x16x32_bf16(pa0, vb0, xacc[0][0], 0, 0, 0);
            xacc[0][1] = __builtin_amdgcn_mfma_f32_16x16x32_bf16(pa0, vb1, xacc[0][1], 0, 0, 0);
            xacc[1][0] = __builtin_amdgcn_mfma_f32_16x16x32_bf16(pa1, vb0, xacc[1][0], 0, 0, 0);
            xacc[1][1] = __builtin_amdgcn_mfma_f32_16x16x32_bf16(pa1, vb1, xacc[1][1], 0, 0, 0);
        }

        // normalized bf16 x -> per-wave transpose buffer (rows local to mtp)
        #pragma unroll
        for (int mf = 0; mf < 2; ++mf)
            #pragma unroll
            for (int nf = 0; nf < 2; ++nf)
                #pragma unroll
                for (int r = 0; r < 4; ++r)
                    xw[(mf * 16 + rg * 4 + r) * 40 + nf * 16 + lr] =
                        (short)f2bf(xacc[mf][nf][r] * linv[mf][r]);

        // frag-linear x store over this head's K-cell frags (tr*8 + wv)
        // (same-wave LDS write->read ordering is in-order on the DS pipe)
        #pragma unroll
        for (int mf = 0; mf < 2; ++mf) {
            int fr = (mtp * 2 + mf) * 8 + wv;
            uint4 v = *(const uint4*)&xw[(mf * 16 + (lane & 15)) * 40
                                         + (lane >> 4) * 8];
            *(uint4*)(kcell + (fr << 9) + lane * 8) = v;
        }
    }
}

// ---------------------------------------------------------------------------
// Kernel 3: out-projection (R5-verbatim). No LDS, no barriers: A (x) and
// B (out-W) frags read coalesced from global; fp32 epilogue into d_out cell.
// ---------------------------------------------------------------------------
__global__ __launch_bounds__(256, 2) void out_proj_mfma(
    short* __restrict__ qkb, const unsigned short* __restrict__ owf,
    const float* __restrict__ ob)
{
    const int tid = threadIdx.x;
    const int lane = tid & 63, wv = tid >> 6;
    const int lr = lane & 15, rg = lane >> 4;
    const int m0 = wv * 32;
    const short* xf = qkb + (size_t)blockIdx.x * 65536 + 32768;
    float* fcell = (float*)qkb + (size_t)blockIdx.x * 32768;

    f32x4 acc[2][16];
    {
        f32x4 z = { 0.f, 0.f, 0.f, 0.f };
        #pragma unroll
        for (int nf = 0; nf < 16; ++nf) { acc[0][nf] = z; acc[1][nf] = z; }
    }

    #pragma unroll
    for (int dc = 0; dc < 8; ++dc) {
        bf16x8 a0 = *(const bf16x8*)(xf + ((((wv * 2 + 0) * 8 + dc) << 9) + lane * 8));
        bf16x8 a1 = *(const bf16x8*)(xf + ((((wv * 2 + 1) * 8 + dc) << 9) + lane * 8));
        #pragma unroll
        for (int nf = 0; nf < 16; ++nf) {
            bf16x8 b = *(const bf16x8*)(owf + (((nf * 8 + dc) << 9) + lane * 8));
            acc[0][nf] = __builtin_amdgcn_mfma_f32_16x16x32_bf16(a0, b, acc[0][nf], 0, 0, 0);
            acc[1][nf] = __builtin_amdgcn_mfma_f32_16x16x32_bf16(a1, b, acc[1][nf], 0, 0, 0);
        }
    }

    #pragma unroll
    for (int mf = 0; mf < 2; ++mf)
        #pragma unroll
        for (int nf = 0; nf < 16; ++nf) {
            float bb = ob[nf * 16 + lr];
            #pragma unroll
            for (int r = 0; r < 4; ++r)
                fcell[(m0 + mf * 16 + rg * 4 + r) * DD + nf * 16 + lr] =
                    acc[mf][nf][r] + bb;
        }
}

extern "C" void kernel_launch(void* const* d_in, const int* in_sizes, int n_in,
                              void* d_out, int out_size, void* d_ws, size_t ws_size,
                              hipStream_t stream) {
    (void)in_sizes; (void)n_in; (void)out_size; (void)ws_size;
    const float* query = (const float*)d_in[0];
    const float* key   = (const float*)d_in[1];
    const float* value = (const float*)d_in[2];
    const void*  kpm   = d_in[3];
    const int*   amask = (const int*)d_in[4];
    const float* wq = (const float*)d_in[5];
    const float* bq = (const float*)d_in[6];
    const float* wk = (const float*)d_in[7];
    const float* bk = (const float*)d_in[8];
    const float* vw = (const float*)d_in[9];
    const float* vb = (const float*)d_in[10];
    const float* ow = (const float*)d_in[11];
    const float* ob = (const float*)d_in[12];

    short* qkb = (short*)d_out;
    unsigned short* wqf = (unsigned short*)d_ws;        // 196608
    unsigned short* wkf = wqf + 196608;                 // 196608
    unsigned short* vwf = wkf + 196608;                 // 65536
    unsigned short* owf = vwf + 65536;                  // 65536  (end 524288)
    int* flagp = (int*)((short*)d_ws + 524288);

    cvt_weights_kernel<<<dim3(1281), dim3(256), 0, stream>>>(
        wq, wk, vw, ow, (const unsigned char*)kpm, wqf, wkf, vwf, owf, flagp);

    proj_kernel<<<dim3(512, 2), dim3(512), 0, stream>>>(
        query, key, wqf, wkf, bq, bk, qkb);

    vproj_attn_fused<<<dim3(512), dim3(512), 0, stream>>>(
        qkb, value, vwf, vb, (const unsigned char*)kpm, (const int*)kpm,
        amask, flagp);

    out_proj_mfma<<<dim3(512), dim3(256), 0, stream>>>(qkb, owf, ob);
}